// Round 6
// baseline (317.976 us; speedup 1.0000x reference)
//
#include <hip/hip_runtime.h>

// Problem constants (fixed by the reference harness)
constexpr int B = 32;
constexpr int T = 4096;   // frames
constexpr int P = 512;    // phonemes
constexpr int H = 512;    // hidden
constexpr int H4 = H / 4; // 128 float4 per row
constexpr int LOG2_H4 = 7;

using f32x4 = __attribute__((ext_vector_type(4))) float;

// ---------------------------------------------------------------------------
// Kernel 1: per-batch inclusive scan of change flags -> packed row data.
// All global accesses coalesced (staged through LDS).
// packed[row] = { bitcast(enc float4-base), pitch[row], beats[row], (float)t }
// ---------------------------------------------------------------------------
__global__ __launch_bounds__(256) void scan_idx_kernel(
    const int* __restrict__ align,
    const float* __restrict__ pitch,
    const float* __restrict__ beats,
    f32x4* __restrict__ packed) {
  const int b = blockIdx.x;
  const int tid = threadIdx.x;
  const long base = (long)b * T;
  constexpr int CH = T / 256; // 16

  __shared__ int s_align[T];  // 16 KB
  __shared__ int sums[256];

  // 1. coalesced load
#pragma unroll
  for (int j = 0; j < CH; ++j)
    s_align[tid + 256 * j] = align[base + tid + 256 * j];
  __syncthreads();

  // 2. local scan of contiguous chunk [start, start+CH)
  const int start = tid * CH;
  int local[CH];
  int prev = (start > 0) ? s_align[start - 1] : s_align[0];
  int run = 0;
#pragma unroll
  for (int j = 0; j < CH; ++j) {
    int a = s_align[start + j];
    run += ((start + j) > 0 && a != prev) ? 1 : 0;
    prev = a;
    local[j] = run;
  }
  sums[tid] = run;
  __syncthreads();

  // 3. Hillis-Steele over per-thread totals
  for (int off = 1; off < 256; off <<= 1) {
    int v = (tid >= off) ? sums[tid - off] : 0;
    __syncthreads();
    sums[tid] += v;
    __syncthreads();
  }
  const int excl = (tid > 0) ? sums[tid - 1] : 0;

  // 4. write clipped idx back into s_align
#pragma unroll
  for (int j = 0; j < CH; ++j) {
    int v = excl + local[j];
    s_align[start + j] = (v > (P - 1)) ? (P - 1) : v;
  }
  __syncthreads();

  // 5. coalesced emit of packed
#pragma unroll
  for (int j = 0; j < CH; ++j) {
    const int t = tid + 256 * j;
    const int v = s_align[t];
    f32x4 pk;
    pk.x = __int_as_float((b * P + v) << LOG2_H4); // enc float4-base
    pk.y = pitch[base + t];
    pk.z = beats[base + t];
    pk.w = (float)t;
    packed[base + t] = pk;
  }
}

// ---------------------------------------------------------------------------
// Kernel 2: swizzled block sw owns 64 CONSECUTIVE rows [sw*64, sw*64+64).
// Chunked XCD swizzle: XCD k gets blocks with contiguous row ranges
// (batches 4k..4k+3) -> 4 MB enc slice resident in its private L2.
// NT stores keep the 256 MB out-stream from evicting that slice.
// ---------------------------------------------------------------------------
__global__ __launch_bounds__(256) void fuse_kernel(
    const f32x4* __restrict__ enc,     // [B*P, H4]
    const f32x4* __restrict__ packed,  // [B*T]
    const f32x4* __restrict__ wp, const f32x4* __restrict__ bp,
    const f32x4* __restrict__ wb, const f32x4* __restrict__ bb,
    const f32x4* __restrict__ wpos, const f32x4* __restrict__ bpos,
    f32x4* __restrict__ out) {         // [B*T, H4]
  const int tid = threadIdx.x;
  const int col = tid & (H4 - 1);
  const int rowHalf = tid >> 7; // 0 or 1

  // Hoisted weights; biases pre-summed.
  const f32x4 w1 = wp[col], w2 = wb[col], w3 = wpos[col];
  const f32x4 cs = bp[col] + bb[col] + bpos[col];

  // Bijective chunked XCD swizzle: 2048 blocks = 8 XCDs x 256.
  const int bid = blockIdx.x;
  const int sw = (bid & 7) * 256 + (bid >> 3);
  const int base = sw * 64;

#pragma unroll 4
  for (int i = 0; i < 16; ++i) {
    const int ra = base + i * 4 + rowHalf;     // rows {base+4i, base+4i+1}
    const int rb = ra + 2;                     // rows {base+4i+2, base+4i+3}
    const int raU = __builtin_amdgcn_readfirstlane(ra);
    const int rbU = __builtin_amdgcn_readfirstlane(rb);
    const f32x4 pka = packed[raU];             // wave-uniform broadcast
    const f32x4 pkb = packed[rbU];
    const f32x4 eva = enc[__float_as_int(pka.x) + col];
    const f32x4 evb = enc[__float_as_int(pkb.x) + col];

    const f32x4 oa = eva + pka.y * w1 + pka.z * w2 + pka.w * w3 + cs;
    const f32x4 ob = evb + pkb.y * w1 + pkb.z * w2 + pkb.w * w3 + cs;

    __builtin_nontemporal_store(oa, &out[((long)ra << LOG2_H4) + col]);
    __builtin_nontemporal_store(ob, &out[((long)rb << LOG2_H4) + col]);
  }
}

extern "C" void kernel_launch(void* const* d_in, const int* in_sizes, int n_in,
                              void* d_out, int out_size, void* d_ws, size_t ws_size,
                              hipStream_t stream) {
  const float* enc     = (const float*)d_in[0]; // [B,P,H]
  const float* pitch   = (const float*)d_in[1]; // [B,T]
  const float* beats   = (const float*)d_in[2]; // [B,T]
  const float* w_pitch = (const float*)d_in[3];
  const float* b_pitch = (const float*)d_in[4];
  const float* w_beats = (const float*)d_in[5];
  const float* b_beats = (const float*)d_in[6];
  const float* w_pos   = (const float*)d_in[7];
  const float* b_pos   = (const float*)d_in[8];
  const int* align     = (const int*)d_in[9];   // [B,T]

  f32x4* packed = (f32x4*)d_ws; // B*T float4 = 2 MB scratch

  scan_idx_kernel<<<B, 256, 0, stream>>>(align, pitch, beats, packed);

  // (B*T)/64 = 2048 blocks, each covering 64 consecutive rows (post-swizzle).
  fuse_kernel<<<(B * T) / 64, 256, 0, stream>>>(
      (const f32x4*)enc, packed,
      (const f32x4*)w_pitch, (const f32x4*)b_pitch,
      (const f32x4*)w_beats, (const f32x4*)b_beats,
      (const f32x4*)w_pos, (const f32x4*)b_pos,
      (f32x4*)d_out);
  (void)in_sizes; (void)n_in; (void)out_size; (void)ws_size;
}